// Round 16
// baseline (1229.613 us; speedup 1.0000x reference)
//
#include <hip/hip_runtime.h>

#define BB 8
#define NN 2048
#define WGS 1024
#define GRID 256
#define NWAVES 16
#define RPW 2                 // rows per wave per batch-half
#define CHUNKS (NN / 64)      // 32
#define MAX_ITER 50
#define NWG_B 64              // WGs arriving per batch barrier (32 prim + 32 sec)

// eps = 0.005; log2 domain: SCL = log2(e)/eps
constexpr float SCL       = 288.5390081777927f;
constexpr float LN2f      = 0.6931471805599453f;
constexpr float EPSf      = 0.005f;
constexpr float EPS_LOGMU = -0.03812309493079699f; // 0.005 * (-ln 2048)

#define SCOPE __HIP_MEMORY_SCOPE_AGENT

__device__ __forceinline__ float aloadf(const float* p){return __hip_atomic_load(p,__ATOMIC_RELAXED,SCOPE);}
__device__ __forceinline__ void  astoref(float* p,float v){__hip_atomic_store(p,v,__ATOMIC_RELAXED,SCOPE);}
__device__ __forceinline__ int   aloadi(const int* p){return __hip_atomic_load(p,__ATOMIC_RELAXED,SCOPE);}

__device__ __forceinline__ float fexp2(float x){return __builtin_amdgcn_exp2f(x);}
__device__ __forceinline__ float flog2(float x){return __builtin_amdgcn_logf(x);}

__device__ __forceinline__ float wsum(float v){
  #pragma unroll
  for (int d = 32; d; d >>= 1) v += __shfl_xor(v, d, 64);
  return v;
}

// Split single-use monotonic barrier (r12-r15 proven semantics).
// barrive: __syncthreads drains every wave's sc1 stores (compiler emits
// per-wave vmcnt(0) before s_barrier), then one far atomicAdd. NO wait.
__device__ __forceinline__ void barrive(int* cnt){
  __syncthreads();
  if (threadIdx.x == 0) {
    asm volatile("s_waitcnt vmcnt(0)" ::: "memory");
    __hip_atomic_fetch_add(cnt, 1, __ATOMIC_RELAXED, SCOPE);
  }
}
// bwait: poll until all arrivals, then WG-wide release. Deadman converts
// any deadlock into a fast wrong answer, never a 600s hang.
__device__ __forceinline__ void bwait(int* cnt, int nwg){
  if (threadIdx.x == 0) {
    int spins = 0;
    while (aloadi(cnt) < nwg) {
      __builtin_amdgcn_s_sleep(1);
      if (++spins > (1 << 17)) break;   // deadman
    }
  }
  __syncthreads();
}
// combined arrive+wait (used once, for the final global barrier)
__device__ __forceinline__ void sbar(int* cnt, int nwg){
  barrive(cnt);
  bwait(cnt, nwg);
}

// One-time prep: pack {x,y,z,|p|^2}; zero 801 single-use counters + accum.
__global__ __launch_bounds__(256) void pack_pts(
    const float* __restrict__ pcs1, const float* __restrict__ pcs2,
    float4* __restrict__ rp1, float4* __restrict__ rp2,
    int* __restrict__ cntArr, float* __restrict__ accum)
{
  int idx = blockIdx.x * 256 + threadIdx.x;
  if (idx == 0) *accum = 0.f;
  if (idx < 801) cntArr[idx * 16] = 0;
  if (idx >= 2 * BB * NN) return;
  if (idx < BB * NN) {
    const float* s = pcs1 + 3 * (size_t)idx;
    float x = s[0], y = s[1], z = s[2];
    rp1[idx] = make_float4(x, y, z, fmaf(x, x, fmaf(y, y, z * z)));
  } else {
    int j = idx - BB * NN;
    const float* s = pcs2 + 3 * (size_t)j;
    float x = s[0], y = s[1], z = s[2];
    rp2[j] = make_float4(x, y, z, fmaf(x, x, fmaf(y, y, z * z)));
  }
}

// One batch-half phase (r15's proven M-free single-pass form, 2 rows/wave).
// Numerics: potentials stay in [-0.1,0.1] -> exp2 args in [+15,-890];
// sub-2^-126 terms flush to 0 against a >=2^-43 max term -> rel err <2^-80;
// fmaxf(S,1e-37) backstops. pot I/O via sc1 atomics only. No trailing
// syncthreads: the following barrive/bwait provides it before J is reused.
__device__ __forceinline__ void half_phase(
    float4* __restrict__ J,
    const float4* __restrict__ RP, const float4* __restrict__ CP,
    const float* __restrict__ potIn, float* __restrict__ potOut,
    int b, int rowbase, int tid, int lane, int wv, bool zero)
{
  const size_t bo = (size_t)b * NN;
  for (int j = tid; j < NN; j += WGS) {
    float4 q = CP[bo + j];                       // plain: pack_pts output
    float pot = zero ? 0.f : aloadf(potIn + bo + j);
    J[j] = make_float4(q.x, q.y, q.z, (pot - q.w) * SCL);
  }
  __syncthreads();

  const int i0 = rowbase + wv * RPW;
  const float4 p0 = RP[bo + i0], p1 = RP[bo + i0 + 1];
  const float X0x=2.f*SCL*p0.x, X0y=2.f*SCL*p0.y, X0z=2.f*SCL*p0.z, B0=-SCL*p0.w;
  const float X1x=2.f*SCL*p1.x, X1y=2.f*SCL*p1.y, X1z=2.f*SCL*p1.z, B1=-SCL*p1.w;

  // unroll capped at 4: full unroll clusters 32 b128 loads -> spill (r1..r5)
  float s0 = 0.f, s1 = 0.f;
  #pragma unroll 4
  for (int k = 0; k < CHUNKS; ++k) {
    float4 q = J[k * 64 + lane];
    s0 += fexp2(fmaf(X0x, q.x, fmaf(X0y, q.y, fmaf(X0z, q.z, q.w + B0))));
    s1 += fexp2(fmaf(X1x, q.x, fmaf(X1y, q.y, fmaf(X1z, q.z, q.w + B1))));
  }
  const float S0 = wsum(s0), S1 = wsum(s1);
  const float o0 = EPS_LOGMU - EPSf*LN2f*flog2(fmaxf(S0, 1e-37f));
  const float o1 = EPS_LOGMU - EPSf*LN2f*flog2(fmaxf(S1, 1e-37f));
  if (lane < 2) astoref(potOut + bo + i0 + lane, lane == 0 ? o0 : o1);
}

// Finalize one batch-half: dist_i = N * sum_j exp2((f_i+g_j-C_ij)*SCL)*C_ij
__device__ __forceinline__ float fin_half(
    float4* __restrict__ J,
    const float4* __restrict__ P1r, const float4* __restrict__ P2r,
    const float* __restrict__ fArr, const float* __restrict__ gArr,
    int b, int rowbase, int tid, int lane, int wv)
{
  const size_t bo = (size_t)b * NN;
  for (int j = tid; j < NN; j += WGS) {
    float4 q = P2r[bo + j];
    J[j] = make_float4(q.x, q.y, q.z, aloadf(gArr + bo + j) * SCL);
  }
  __syncthreads();

  const int i0 = rowbase + wv * RPW;
  float part = 0.f;
  #pragma unroll 1
  for (int r = 0; r < RPW; ++r) {
    const int i = i0 + r;
    const float4 p = P1r[bo + i];
    const float Fi = aloadf(fArr + bo + i) * SCL;
    float a0 = 0.f, a1 = 0.f;
    #pragma unroll 2
    for (int k = 0; k < CHUNKS; k += 2) {
      float4 qa = J[k * 64 + lane];
      float4 qb = J[(k + 1) * 64 + lane];
      float dxa = p.x - qa.x, dya = p.y - qa.y, dza = p.z - qa.z;
      float ca = fmaf(dxa, dxa, fmaf(dya, dya, dza * dza));
      a0 = fmaf(fexp2(fmaf(-SCL, ca, Fi + qa.w)), ca, a0);
      float dxb = p.x - qb.x, dyb = p.y - qb.y, dzb = p.z - qb.z;
      float cb = fmaf(dxb, dxb, fmaf(dyb, dyb, dzb * dzb));
      a1 = fmaf(fexp2(fmaf(-SCL, cb, Fi + qb.w)), cb, a1);
    }
    float lacc = wsum(a0 + a1);
    if (lane == 0) part += sqrtf((float)NN * lacc + 1e-12f);
  }
  return part;
}

// DUAL-BATCH deferred-wait pipeline: each WG serves batches b0=wg>>5 and
// b1=b0^4 (64 WGs/batch, 32 rows each: primary rows [sub*32,+32), secondary
// rows [1024+sub*32,+32)). Every bwait is preceded by a half-phase of
// independent work on the other batch -> barrier latency + skew hidden.
// Deadlock-free: barrier slots are totally time-ordered and each arrival
// depends only on strictly older slots (induction from t=0).
__global__ __launch_bounds__(WGS) void emd_sinkhorn_fused(
    const float4* __restrict__ P1r, const float4* __restrict__ P2r,
    float* __restrict__ fArr, float* __restrict__ gArr,
    int* __restrict__ cntArr, float* __restrict__ accum,
    float* __restrict__ out)
{
  __shared__ float4 J[NN];
  __shared__ float red[NWAVES];
  const int wg = blockIdx.x, tid = threadIdx.x;
  const int b0 = wg >> 5, sub = wg & 31, b1 = b0 ^ 4;
  const int lane = tid & 63, wv = tid >> 6;
  const int row0 = sub * 32;          // this WG's rows in b0
  const int row1 = 1024 + sub * 32;   // this WG's rows in b1

  #define FBAR(t, b) (cntArr + ((2 * (t)) * 8 + (b)) * 16)
  #define GBAR(t, b) (cntArr + ((2 * (t) + 1) * 8 + (b)) * 16)

  for (int t = 0; t < MAX_ITER; ++t) {
    if (t) bwait(GBAR(t - 1, b0), NWG_B);        // hidden by prev G_b1 work
    half_phase(J, P1r, P2r, gArr, fArr, b0, row0, tid, lane, wv, t == 0);
    barrive(FBAR(t, b0));
    if (t) bwait(GBAR(t - 1, b1), NWG_B);        // hidden by F_b0 work
    half_phase(J, P1r, P2r, gArr, fArr, b1, row1, tid, lane, wv, t == 0);
    barrive(FBAR(t, b1));
    bwait(FBAR(t, b0), NWG_B);                   // hidden by F_b1 work
    half_phase(J, P2r, P1r, fArr, gArr, b0, row0, tid, lane, wv, false);
    barrive(GBAR(t, b0));
    bwait(FBAR(t, b1), NWG_B);                   // hidden by G_b0 work
    half_phase(J, P2r, P1r, fArr, gArr, b1, row1, tid, lane, wv, false);
    barrive(GBAR(t, b1));
  }

  float part = 0.f;
  bwait(GBAR(MAX_ITER - 1, b0), NWG_B);          // hidden by G_b1 work
  part += fin_half(J, P1r, P2r, fArr, gArr, b0, row0, tid, lane, wv);
  bwait(GBAR(MAX_ITER - 1, b1), NWG_B);          // hidden by b0 finalize
  part += fin_half(J, P1r, P2r, fArr, gArr, b1, row1, tid, lane, wv);

  if (lane == 0) red[wv] = part;
  __syncthreads();
  if (tid == 0) {
    float s = 0.f;
    #pragma unroll
    for (int w = 0; w < NWAVES; ++w) s += red[w];
    atomicAdd(accum, s);
  }
  sbar(cntArr + 800 * 16, GRID);                 // global: all partials landed
  if (wg == 0 && tid == 0) out[0] = aloadf(accum) * (1.f / 16384.f);
}

extern "C" void kernel_launch(void* const* d_in, const int* in_sizes, int n_in,
                              void* d_out, int out_size, void* d_ws, size_t ws_size,
                              hipStream_t stream) {
  const float* pcs1 = (const float*)d_in[0];
  const float* pcs2 = (const float*)d_in[1];
  float* out = (float*)d_out;
  char*  base = (char*)d_ws;
  float* fArr   = (float*)base;                    // 64KB
  float* gArr   = (float*)(base + 64 * 1024);      // 64KB
  float* accum  = (float*)(base + 128 * 1024);     // 1 float
  int*   cntArr = (int*)(base + 192 * 1024);       // 801 x 64B
  float4* P1r   = (float4*)(base + 512 * 1024);    // 256KB
  float4* P2r   = (float4*)(base + 768 * 1024);    // 256KB

  pack_pts<<<(2 * BB * NN + 255) / 256, 256, 0, stream>>>(
      pcs1, pcs2, P1r, P2r, cntArr, accum);

  // plain launch (r13/r14: coop API silently no-ops >256 blocks @1024thr;
  // 256 blocks = 1 WG/CU is trivially co-resident)
  emd_sinkhorn_fused<<<GRID, WGS, 0, stream>>>(
      P1r, P2r, fArr, gArr, cntArr, accum, out);
}

// Round 17
// 748.686 us; speedup vs baseline: 1.6424x; 1.6424x over previous
//
#include <hip/hip_runtime.h>

#define BB 8
#define NN 2048
#define WGS 1024
#define GRID 256
#define WG_PER_B 32           // WGs per batch
#define ROWS_WG 64            // rows per WG
#define NWAVES 16
#define RPW 4                 // rows per wave
#define CHUNKS 32             // NN/64
#define MAX_ITER 50
#define REDPAD 4160           // LDS pad: total >81920B -> 1 WG/CU -> 128 VGPR budget

// eps = 0.005; log2 domain: SCL = log2(e)/eps
constexpr float SCL       = 288.5390081777927f;
constexpr float LN2f      = 0.6931471805599453f;
constexpr float EPSf      = 0.005f;
constexpr float EPS_LOGMU = -0.03812309493079699f; // 0.005 * (-ln 2048)

#define SCOPE __HIP_MEMORY_SCOPE_AGENT

__device__ __forceinline__ float aloadf(const float* p){return __hip_atomic_load(p,__ATOMIC_RELAXED,SCOPE);}
__device__ __forceinline__ void  astoref(float* p,float v){__hip_atomic_store(p,v,__ATOMIC_RELAXED,SCOPE);}
__device__ __forceinline__ int   aloadi(const int* p){return __hip_atomic_load(p,__ATOMIC_RELAXED,SCOPE);}

__device__ __forceinline__ float fexp2(float x){return __builtin_amdgcn_exp2f(x);}
__device__ __forceinline__ float flog2(float x){return __builtin_amdgcn_logf(x);}

__device__ __forceinline__ float wsum(float v){
  #pragma unroll
  for (int d = 32; d; d >>= 1) v += __shfl_xor(v, d, 64);
  return v;
}

// FLAG-ARRAY single-use barrier: WG `sub` STORES 1 into its own slot (no
// RMW -> zero arrival serialization, vs 32 serialized atomicAdds ~1.6us).
// Waiters: wave-0 lanes each poll one flag (one coalesced 128B load/round)
// until all 32 are set. Single-use/monotonic (0->1 only): no ABA class.
// Deadman converts any deadlock into a fast wrong answer, never a hang.
__device__ __forceinline__ void flag_arrive(int* flags, int sub){
  __syncthreads();                     // per-wave vmcnt(0) drains pot stores
  if (threadIdx.x == 0) {
    asm volatile("s_waitcnt vmcnt(0)" ::: "memory");
    __hip_atomic_store(flags + sub, 1, __ATOMIC_RELAXED, SCOPE);
  }
}
__device__ __forceinline__ void flag_wait(const int* flags){
  if (threadIdx.x < 64) {
    const int* fp = flags + (threadIdx.x & 31);
    int spins = 0;
    while (!__all(aloadi(fp) != 0)) {
      __builtin_amdgcn_s_sleep(1);
      if (++spins > (1 << 17)) break;  // deadman
    }
  }
  __syncthreads();
}
// counter barrier for the single final global sync (latency-irrelevant)
__device__ __forceinline__ void sbar(int* cnt, int nwg){
  __syncthreads();
  if (threadIdx.x == 0) {
    asm volatile("s_waitcnt vmcnt(0)" ::: "memory");
    __hip_atomic_fetch_add(cnt, 1, __ATOMIC_RELAXED, SCOPE);
    int spins = 0;
    while (aloadi(cnt) < nwg) {
      __builtin_amdgcn_s_sleep(1);
      if (++spins > (1 << 17)) break;
    }
  }
  __syncthreads();
}

// One-time prep: pack {x,y,z,|p|^2}; zero 800x32 barrier flags + final
// counter + accum.
__global__ __launch_bounds__(256) void pack_pts(
    const float* __restrict__ pcs1, const float* __restrict__ pcs2,
    float4* __restrict__ rp1, float4* __restrict__ rp2,
    int* __restrict__ flags, float* __restrict__ accum)
{
  int idx = blockIdx.x * 256 + threadIdx.x;
  if (idx == 0) *accum = 0.f;
  if (idx < 800 * 32 + 16) flags[idx] = 0;
  if (idx >= 2 * BB * NN) return;
  if (idx < BB * NN) {
    const float* s = pcs1 + 3 * (size_t)idx;
    float x = s[0], y = s[1], z = s[2];
    rp1[idx] = make_float4(x, y, z, fmaf(x, x, fmaf(y, y, z * z)));
  } else {
    int j = idx - BB * NN;
    const float* s = pcs2 + 3 * (size_t)j;
    float x = s[0], y = s[1], z = s[2];
    rp2[j] = make_float4(x, y, z, fmaf(x, x, fmaf(y, y, z * z)));
  }
}

// Fused Sinkhorn. Persistent LDS coords (JF=pcs2 cols, JG=pcs1 cols) staged
// once; per phase only the .w field is rewritten (2 far pot loads + 2
// ds_write_b32 per thread) — no per-phase 16B/point restage. Row constants
// are loop-invariant and hoisted (rows fixed per wave for all 50 iters).
// M-free numerics proven in r15 (exp2 args in [+15,-890]; flushed terms
// lose <2^-80 relative; fmaxf backstop). pot I/O via sc1 atomics only.
__global__ __launch_bounds__(WGS) void emd_sinkhorn_fused(
    const float4* __restrict__ P1r, const float4* __restrict__ P2r,
    float* __restrict__ fArr, float* __restrict__ gArr,
    int* __restrict__ flags, float* __restrict__ accum,
    float* __restrict__ out)
{
  __shared__ float4 JF[NN];            // {x,y,z, (g_j - qq2_j)*SCL}
  __shared__ float4 JG[NN];            // {x,y,z, (f_j - qq1_j)*SCL}
  __shared__ float red[REDPAD];        // oversized: LDS occupancy pad (r5)

  const int wg = blockIdx.x, tid = threadIdx.x;
  const int b = wg / WG_PER_B, sub = wg % WG_PER_B;
  const int lane = tid & 63, wv = tid >> 6;
  const size_t bo = (size_t)b * NN;
  const int j0 = tid, j1 = tid + 1024;

  // persistent coords into LDS; per-thread qq*SCL stays in registers
  const float4 c2a = P2r[bo + j0], c2b = P2r[bo + j1];
  const float4 c1a = P1r[bo + j0], c1b = P1r[bo + j1];
  const float q2s0 = c2a.w * SCL, q2s1 = c2b.w * SCL;
  const float q1s0 = c1a.w * SCL, q1s1 = c1b.w * SCL;
  JF[j0] = make_float4(c2a.x, c2a.y, c2a.z, -q2s0);   // t=0: g == 0
  JF[j1] = make_float4(c2b.x, c2b.y, c2b.z, -q2s1);
  JG[j0] = make_float4(c1a.x, c1a.y, c1a.z, 0.f);
  JG[j1] = make_float4(c1b.x, c1b.y, c1b.z, 0.f);

  // loop-invariant row constants
  const int i0 = sub * ROWS_WG + wv * RPW;
  const float4 fp0 = P1r[bo+i0], fp1 = P1r[bo+i0+1], fp2 = P1r[bo+i0+2], fp3 = P1r[bo+i0+3];
  const float4 gp0 = P2r[bo+i0], gp1 = P2r[bo+i0+1], gp2 = P2r[bo+i0+2], gp3 = P2r[bo+i0+3];
  const float fX0x=2.f*SCL*fp0.x, fX0y=2.f*SCL*fp0.y, fX0z=2.f*SCL*fp0.z, fB0=-SCL*fp0.w;
  const float fX1x=2.f*SCL*fp1.x, fX1y=2.f*SCL*fp1.y, fX1z=2.f*SCL*fp1.z, fB1=-SCL*fp1.w;
  const float fX2x=2.f*SCL*fp2.x, fX2y=2.f*SCL*fp2.y, fX2z=2.f*SCL*fp2.z, fB2=-SCL*fp2.w;
  const float fX3x=2.f*SCL*fp3.x, fX3y=2.f*SCL*fp3.y, fX3z=2.f*SCL*fp3.z, fB3=-SCL*fp3.w;
  const float gX0x=2.f*SCL*gp0.x, gX0y=2.f*SCL*gp0.y, gX0z=2.f*SCL*gp0.z, gB0=-SCL*gp0.w;
  const float gX1x=2.f*SCL*gp1.x, gX1y=2.f*SCL*gp1.y, gX1z=2.f*SCL*gp1.z, gB1=-SCL*gp1.w;
  const float gX2x=2.f*SCL*gp2.x, gX2y=2.f*SCL*gp2.y, gX2z=2.f*SCL*gp2.z, gB2=-SCL*gp2.w;
  const float gX3x=2.f*SCL*gp3.x, gX3y=2.f*SCL*gp3.y, gX3z=2.f*SCL*gp3.z, gB3=-SCL*gp3.w;

  #define BARF(t) (flags + ((2 * (t))     * 8 + b) * 32)
  #define BARG(t) (flags + ((2 * (t) + 1) * 8 + b) * 32)

  for (int t = 0; t < MAX_ITER; ++t) {
    // ---- f-phase: cols JF (pcs2 + g), rows pcs1
    if (t) {
      flag_wait(BARG(t - 1));
      const float ga = aloadf(gArr + bo + j0), gb = aloadf(gArr + bo + j1);
      JF[j0].w = fmaf(ga, SCL, -q2s0);
      JF[j1].w = fmaf(gb, SCL, -q2s1);
    }
    __syncthreads();
    {
      float s0 = 0.f, s1 = 0.f, s2 = 0.f, s3 = 0.f;
      #pragma unroll 4
      for (int k = 0; k < CHUNKS; ++k) {
        float4 q = JF[k * 64 + lane];
        s0 += fexp2(fmaf(fX0x, q.x, fmaf(fX0y, q.y, fmaf(fX0z, q.z, q.w + fB0))));
        s1 += fexp2(fmaf(fX1x, q.x, fmaf(fX1y, q.y, fmaf(fX1z, q.z, q.w + fB1))));
        s2 += fexp2(fmaf(fX2x, q.x, fmaf(fX2y, q.y, fmaf(fX2z, q.z, q.w + fB2))));
        s3 += fexp2(fmaf(fX3x, q.x, fmaf(fX3y, q.y, fmaf(fX3z, q.z, q.w + fB3))));
      }
      const float S0 = wsum(s0), S1 = wsum(s1), S2 = wsum(s2), S3 = wsum(s3);
      const float o0 = EPS_LOGMU - EPSf*LN2f*flog2(fmaxf(S0, 1e-37f));
      const float o1 = EPS_LOGMU - EPSf*LN2f*flog2(fmaxf(S1, 1e-37f));
      const float o2 = EPS_LOGMU - EPSf*LN2f*flog2(fmaxf(S2, 1e-37f));
      const float o3 = EPS_LOGMU - EPSf*LN2f*flog2(fmaxf(S3, 1e-37f));
      const float oo = lane == 0 ? o0 : (lane == 1 ? o1 : (lane == 2 ? o2 : o3));
      if (lane < 4) astoref(fArr + bo + i0 + lane, oo);
    }
    flag_arrive(BARF(t), sub);

    // ---- g-phase: cols JG (pcs1 + f), rows pcs2
    flag_wait(BARF(t));
    {
      const float fa = aloadf(fArr + bo + j0), fb = aloadf(fArr + bo + j1);
      JG[j0].w = fmaf(fa, SCL, -q1s0);
      JG[j1].w = fmaf(fb, SCL, -q1s1);
    }
    __syncthreads();
    {
      float s0 = 0.f, s1 = 0.f, s2 = 0.f, s3 = 0.f;
      #pragma unroll 4
      for (int k = 0; k < CHUNKS; ++k) {
        float4 q = JG[k * 64 + lane];
        s0 += fexp2(fmaf(gX0x, q.x, fmaf(gX0y, q.y, fmaf(gX0z, q.z, q.w + gB0))));
        s1 += fexp2(fmaf(gX1x, q.x, fmaf(gX1y, q.y, fmaf(gX1z, q.z, q.w + gB1))));
        s2 += fexp2(fmaf(gX2x, q.x, fmaf(gX2y, q.y, fmaf(gX2z, q.z, q.w + gB2))));
        s3 += fexp2(fmaf(gX3x, q.x, fmaf(gX3y, q.y, fmaf(gX3z, q.z, q.w + gB3))));
      }
      const float S0 = wsum(s0), S1 = wsum(s1), S2 = wsum(s2), S3 = wsum(s3);
      const float o0 = EPS_LOGMU - EPSf*LN2f*flog2(fmaxf(S0, 1e-37f));
      const float o1 = EPS_LOGMU - EPSf*LN2f*flog2(fmaxf(S1, 1e-37f));
      const float o2 = EPS_LOGMU - EPSf*LN2f*flog2(fmaxf(S2, 1e-37f));
      const float o3 = EPS_LOGMU - EPSf*LN2f*flog2(fmaxf(S3, 1e-37f));
      const float oo = lane == 0 ? o0 : (lane == 1 ? o1 : (lane == 2 ? o2 : o3));
      if (lane < 4) astoref(gArr + bo + i0 + lane, oo);
    }
    flag_arrive(BARG(t), sub);
  }

  // ---- finalize: dist_i = N * sum_j exp2((f_i+g_j-C_ij)*SCL) * C_ij
  flag_wait(BARG(MAX_ITER - 1));
  {
    const float ga = aloadf(gArr + bo + j0), gb = aloadf(gArr + bo + j1);
    JF[j0].w = ga * SCL;                 // coords persist; w := g*SCL
    JF[j1].w = gb * SCL;
  }
  __syncthreads();

  const float4 prs[RPW] = { fp0, fp1, fp2, fp3 };
  float part = 0.f;
  #pragma unroll
  for (int r = 0; r < RPW; ++r) {
    const float4 p = prs[r];
    const float Fi = aloadf(fArr + bo + i0 + r) * SCL;
    float a0 = 0.f, a1 = 0.f;
    #pragma unroll 2
    for (int k = 0; k < CHUNKS; k += 2) {
      float4 qa = JF[k * 64 + lane];
      float4 qb = JF[(k + 1) * 64 + lane];
      float dxa = p.x - qa.x, dya = p.y - qa.y, dza = p.z - qa.z;
      float ca = fmaf(dxa, dxa, fmaf(dya, dya, dza * dza));
      a0 = fmaf(fexp2(fmaf(-SCL, ca, Fi + qa.w)), ca, a0);
      float dxb = p.x - qb.x, dyb = p.y - qb.y, dzb = p.z - qb.z;
      float cb = fmaf(dxb, dxb, fmaf(dyb, dyb, dzb * dzb));
      a1 = fmaf(fexp2(fmaf(-SCL, cb, Fi + qb.w)), cb, a1);
    }
    float lacc = wsum(a0 + a1);
    if (lane == 0) part += sqrtf((float)NN * lacc + 1e-12f);
  }
  if (lane == 0) red[wv] = part;
  __syncthreads();
  if (tid == 0) {
    float s = 0.f;
    #pragma unroll
    for (int w = 0; w < NWAVES; ++w) s += red[w];
    atomicAdd(accum, s);
  }
  sbar(flags + 800 * 32, GRID);          // final global barrier (counter)
  if (wg == 0 && tid == 0) out[0] = aloadf(accum) * (1.f / 16384.f);
}

extern "C" void kernel_launch(void* const* d_in, const int* in_sizes, int n_in,
                              void* d_out, int out_size, void* d_ws, size_t ws_size,
                              hipStream_t stream) {
  const float* pcs1 = (const float*)d_in[0];
  const float* pcs2 = (const float*)d_in[1];
  float* out = (float*)d_out;
  char*  base = (char*)d_ws;
  float* fArr   = (float*)base;                    // 64KB
  float* gArr   = (float*)(base + 64 * 1024);      // 64KB
  float* accum  = (float*)(base + 128 * 1024);     // 1 float
  int*   flags  = (int*)(base + 192 * 1024);       // 800x32 ints + final cnt (~103KB)
  float4* P1r   = (float4*)(base + 512 * 1024);    // 256KB
  float4* P2r   = (float4*)(base + 768 * 1024);    // 256KB

  pack_pts<<<(2 * BB * NN + 255) / 256, 256, 0, stream>>>(
      pcs1, pcs2, P1r, P2r, flags, accum);

  // plain launch (r13/r14: coop API silently no-ops >256 blocks @1024thr;
  // 256 blocks = 1 WG/CU is trivially co-resident)
  emd_sinkhorn_fused<<<GRID, WGS, 0, stream>>>(
      P1r, P2r, fArr, gArr, flags, accum, out);
}